// Round 7
// baseline (1366.101 us; speedup 1.0000x reference)
//
#include <hip/hip_runtime.h>
#include <hip/hip_bf16.h>

#define IN_CH 128
#define OUT_CH 256

typedef __bf16 bf16x8 __attribute__((ext_vector_type(8)));
typedef float f32x4 __attribute__((ext_vector_type(4)));

__device__ inline unsigned short f2bf(float f) {
  union { float f; unsigned int u; } v; v.f = f;
  unsigned int u = v.u;
  u += 0x7FFFu + ((u >> 16) & 1u);   // round-to-nearest-even
  return (unsigned short)(u >> 16);
}

// Bpack element layout (ushort): idx = (((tn*4+ks)*4+kb)*16 + c)*8 + j
//   value = bf16( W[tn*16+c][ks*32 + kb*8 + j] )
// Same (kb,j)->k convention as the A-fragments, so the k-permutation cancels.
__global__ void init_kernel(const float* __restrict__ W, unsigned short* __restrict__ Bpack) {
  int i = blockIdx.x * blockDim.x + threadIdx.x;
  if (i < IN_CH * OUT_CH) {
    const int j  = i & 7;
    const int c  = (i >> 3) & 15;
    const int kb = (i >> 7) & 3;
    const int ks = (i >> 9) & 3;
    const int tn = i >> 11;
    Bpack[i] = f2bf(W[(size_t)(tn * 16 + c) * IN_CH + ks * 32 + kb * 8 + j]);
  }
}

// Edge-order streaming scatter-add.
// One wave per 4 consecutive edges per iteration: 64 lanes x float2 = one 512B
// row per load (te read is a pure sequential stream), then 8 fire-and-forget
// global_atomic_add_f32 per lane-pair into agg[col[e]][:]. No loop-carried
// dependency -> naturally pipelined; atomics resolve at the coherent point
// (agg = 51MB, L3-resident) without stalling the wave.
__global__ __launch_bounds__(256) void scatter_add_kernel(
    const float* __restrict__ te, const int* __restrict__ col,
    float* __restrict__ agg, int E) {
  const int lane = threadIdx.x & 63;
  const int gw   = (blockIdx.x * 256 + threadIdx.x) >> 6;   // global wave id
  const int nw   = (gridDim.x * 256) >> 6;
  const int co   = lane * 2;
  for (int base = gw * 4; base < E; base += nw * 4) {
    if (base + 4 <= E) {
      const int c0 = col[base + 0];
      const int c1 = col[base + 1];
      const int c2 = col[base + 2];
      const int c3 = col[base + 3];
      const float2 v0 = *(const float2*)(te + (size_t)(base + 0) * IN_CH + co);
      const float2 v1 = *(const float2*)(te + (size_t)(base + 1) * IN_CH + co);
      const float2 v2 = *(const float2*)(te + (size_t)(base + 2) * IN_CH + co);
      const float2 v3 = *(const float2*)(te + (size_t)(base + 3) * IN_CH + co);
      float* p0 = agg + (size_t)c0 * IN_CH + co;
      float* p1 = agg + (size_t)c1 * IN_CH + co;
      float* p2 = agg + (size_t)c2 * IN_CH + co;
      float* p3 = agg + (size_t)c3 * IN_CH + co;
      unsafeAtomicAdd(p0, v0.x); unsafeAtomicAdd(p0 + 1, v0.y);
      unsafeAtomicAdd(p1, v1.x); unsafeAtomicAdd(p1 + 1, v1.y);
      unsafeAtomicAdd(p2, v2.x); unsafeAtomicAdd(p2 + 1, v2.y);
      unsafeAtomicAdd(p3, v3.x); unsafeAtomicAdd(p3 + 1, v3.y);
    } else {
      for (int e = base; e < E; ++e) {
        const int c = col[e];
        const float2 v = *(const float2*)(te + (size_t)e * IN_CH + co);
        float* p = agg + (size_t)c * IN_CH + co;
        unsafeAtomicAdd(p, v.x); unsafeAtomicAdd(p + 1, v.y);
      }
    }
  }
}

// MFMA projection: C[N,256] = bf16(agg[N,128]) @ W^T + b.
// A frag: lane(r=lane&15, kb=lane>>4) holds agg[m0+r][ks*32+kb*8 .. +8],
// converted fp32->bf16 in-register. C/D: col=lane&15, row=(lane>>4)*4+reg.
__global__ __launch_bounds__(256) void project_mfma(
    const float* __restrict__ agg, const unsigned short* __restrict__ Bpack,
    const float* __restrict__ bias, float* __restrict__ out, int N) {
  const int wave = threadIdx.x >> 6;
  const int lane = threadIdx.x & 63;
  const int r  = lane & 15;
  const int kb = lane >> 4;
  const int m0 = blockIdx.x * 16;
  const int rr = (m0 + r < N) ? (m0 + r) : (N - 1);

  bf16x8 a[4];
  const float* arow = agg + (size_t)rr * IN_CH + kb * 8;
#pragma unroll
  for (int ks = 0; ks < 4; ++ks) {
    const f32x4 lo = *(const f32x4*)(arow + ks * 32);
    const f32x4 hi = *(const f32x4*)(arow + ks * 32 + 4);
    bf16x8 t;
    t[0] = (__bf16)lo[0]; t[1] = (__bf16)lo[1]; t[2] = (__bf16)lo[2]; t[3] = (__bf16)lo[3];
    t[4] = (__bf16)hi[0]; t[5] = (__bf16)hi[1]; t[6] = (__bf16)hi[2]; t[7] = (__bf16)hi[3];
    a[ks] = t;
  }

  f32x4 acc[4];
#pragma unroll
  for (int ct = 0; ct < 4; ++ct) acc[ct] = (f32x4){0.f, 0.f, 0.f, 0.f};

#pragma unroll
  for (int ct = 0; ct < 4; ++ct) {
    const int tn = wave * 4 + ct;
#pragma unroll
    for (int ks = 0; ks < 4; ++ks) {
      const bf16x8 b = *(const bf16x8*)(Bpack + (size_t)((((tn * 4 + ks) * 4 + kb) * 16 + r) * 8));
      acc[ct] = __builtin_amdgcn_mfma_f32_16x16x32_bf16(a[ks], b, acc[ct], 0, 0, 0);
    }
  }

#pragma unroll
  for (int ct = 0; ct < 4; ++ct) {
    const int colo = wave * 64 + ct * 16 + r;
    const float bv = bias[colo];
#pragma unroll
    for (int j = 0; j < 4; ++j) {
      const int m = m0 + kb * 4 + j;
      if (m < N) out[(size_t)m * OUT_CH + colo] = acc[ct][j] + bv;
    }
  }
}

extern "C" void kernel_launch(void* const* d_in, const int* in_sizes, int n_in,
                              void* d_out, int out_size, void* d_ws, size_t ws_size,
                              hipStream_t stream) {
  const int* edge_index = (const int*)d_in[0];
  const float* te       = (const float*)d_in[1];
  const float* W        = (const float*)d_in[3];
  const float* bias     = (const float*)d_in[4];
  float* out            = (float*)d_out;

  const int E = in_sizes[0] / 2;
  const int N = out_size / OUT_CH;
  const int* col = edge_index + E;  // edge_index[1]

  // workspace: Bpack (64KB) | agg (N*128 f32)
  unsigned short* Bpack = (unsigned short*)d_ws;
  float* agg = (float*)((char*)d_ws + 65536);

  hipMemsetAsync(agg, 0, (size_t)N * IN_CH * sizeof(float), stream);
  hipLaunchKernelGGL(init_kernel, dim3((IN_CH * OUT_CH + 255) / 256), dim3(256), 0, stream,
                     W, Bpack);
  hipLaunchKernelGGL(scatter_add_kernel, dim3(2048), dim3(256), 0, stream, te, col, agg, E);
  hipLaunchKernelGGL(project_mfma, dim3((N + 15) / 16), dim3(256), 0, stream,
                     agg, Bpack, bias, out, N);
}